// Round 6
// baseline (859.152 us; speedup 1.0000x reference)
//
#include <hip/hip_runtime.h>
#include <math.h>

// HungarianLoss: B=128 samples, each a 192x192 LSAP on
// cost[q][j] = -softmax(pred[q])[tgt[j]], then mean CE with matched classes.
//
// R6 = R5 (sequential JV shortest augmenting path, zero duals, all state in
// registers 3/lane, packed u32 argmin reduce) with the per-settle critical
// path trimmed:
//  - cost stored [q][64][3] so each lane's 3 cols are one ds_read_b96
//  - r = c + sv with sv = (minVal - u[i]) - v[j] precomputed in the LDS
//    shadow (settled-guard folded into sv) -> post-data chain is 1 add
//  - running packed key kp = umin(kp, bits(r+1.0)&~255 | col): argmin chain
//    decoupled from the spc/p float updates
//  - 1-step searches (sink on first settle) skip the dual/augment epilogue

#define BB 128
#define QQ 192
#define CC 512
#define NBIG 1e30f

template<int CTRL>
__device__ __forceinline__ int dpp_mov(int x) {
    return __builtin_amdgcn_update_dpp(x, x, CTRL, 0xf, 0xf, false);
}

__device__ __forceinline__ int readlane_i(int v, int l) {
    return __builtin_amdgcn_readlane(v, l);
}
__device__ __forceinline__ float readlane_f(float v, int l) {
    return __int_as_float(__builtin_amdgcn_readlane(__float_as_int(v), l));
}
__device__ __forceinline__ unsigned umin_(unsigned a, unsigned b) { return a < b ? a : b; }

// fill-phase reduces (validated R1-R5)
__device__ __forceinline__ float wave_max64(float x) {
    x = fmaxf(x, __int_as_float(dpp_mov<0x111>(__float_as_int(x))));
    x = fmaxf(x, __int_as_float(dpp_mov<0x112>(__float_as_int(x))));
    x = fmaxf(x, __int_as_float(dpp_mov<0x114>(__float_as_int(x))));
    x = fmaxf(x, __int_as_float(dpp_mov<0x118>(__float_as_int(x))));
    x = fmaxf(x, __int_as_float(dpp_mov<0x142>(__float_as_int(x))));
    x = fmaxf(x, __int_as_float(dpp_mov<0x143>(__float_as_int(x))));
    return __int_as_float(__builtin_amdgcn_readlane(__float_as_int(x), 63));
}
__device__ __forceinline__ float wave_sum64(float x) {
    x += __int_as_float(dpp_mov<0x111>(__float_as_int(x)));
    x += __int_as_float(dpp_mov<0x112>(__float_as_int(x)));
    x += __int_as_float(dpp_mov<0x114>(__float_as_int(x)));
    x += __int_as_float(dpp_mov<0x118>(__float_as_int(x)));
    x += __int_as_float(dpp_mov<0x142>(__float_as_int(x)));
    x += __int_as_float(dpp_mov<0x143>(__float_as_int(x)));
    return __int_as_float(__builtin_amdgcn_readlane(__float_as_int(x), 63));
}

// packed-key min over 64 lanes: 4 DPP row_shr + 4 readlane + 3 scalar min
__device__ __forceinline__ unsigned wave_min_pk(unsigned x) {
    x = umin_(x, (unsigned)dpp_mov<0x111>((int)x));
    x = umin_(x, (unsigned)dpp_mov<0x112>((int)x));
    x = umin_(x, (unsigned)dpp_mov<0x114>((int)x));
    x = umin_(x, (unsigned)dpp_mov<0x118>((int)x));
    unsigned a = (unsigned)readlane_i((int)x, 15);
    unsigned b = (unsigned)readlane_i((int)x, 31);
    unsigned c = (unsigned)readlane_i((int)x, 47);
    unsigned d = (unsigned)readlane_i((int)x, 63);
    return umin_(umin_(a, b), umin_(c, d));
}

// distributed-register accessors (idx -> owner lane idx&63, slot idx>>6)
#define GET_I3(a, idx) readlane_i((((idx)>>6)==0) ? a##0 : ((((idx)>>6)==1) ? a##1 : a##2), (idx)&63)
#define GET_F3(a, idx) readlane_f((((idx)>>6)==0) ? a##0 : ((((idx)>>6)==1) ? a##1 : a##2), (idx)&63)
#define SET_I3(a, idx, val) do { const int _s=(idx)>>6, _l=(idx)&63; \
    if (_s==0) { if (lane==_l) a##0=(val); } \
    else if (_s==1) { if (lane==_l) a##1=(val); } \
    else { if (lane==_l) a##2=(val); } } while(0)

__launch_bounds__(256)
__global__ void hungarian_kernel(const float* __restrict__ pred,
                                 const int* __restrict__ targets,
                                 float* __restrict__ ws_part) {
    const int b = blockIdx.x;
    const int lane = threadIdx.x & 63;
    const int wv = threadIdx.x >> 6;

    extern __shared__ float smem[];
    float* cost    = smem;                   // [QQ][64][3]: col j at q*192 + (j&63)*3 + (j>>6)
    float* spc_lds = cost + QQ * QQ;         // [QQ] per-solve spc dump (indexed by col)
    float* lse_lds = spc_lds + QQ;           // [QQ]
    int*   tgt_lds = (int*)(lse_lds + QQ);   // [QQ]

    // ---- targets ----
    const int t0 = targets[b * QQ + lane];
    const int t1 = targets[b * QQ + lane + 64];
    const int t2 = targets[b * QQ + lane + 128];
    if (wv == 0) { tgt_lds[lane] = t0; tgt_lds[lane + 64] = t1; tgt_lds[lane + 128] = t2; }

    // ---- fill: 4 waves, 48 rows each; lane writes its 3 cols contiguously ----
    const float* predb = pred + (size_t)b * QQ * CC;
    {
        const int q0 = wv * 48, q1 = q0 + 48;
        float x[8];
        #pragma unroll
        for (int k = 0; k < 8; k++) x[k] = predb[(size_t)q0 * CC + lane + 64 * k];
        for (int q = q0; q < q1; q++) {
            const float* row = predb + (size_t)q * CC;
            float g0 = row[t0], g1 = row[t1], g2 = row[t2];
            float xn[8];
            if (q + 1 < q1) {
                const float* nrow = row + CC;
                #pragma unroll
                for (int k = 0; k < 8; k++) xn[k] = nrow[lane + 64 * k];
            }
            float mx = x[0];
            #pragma unroll
            for (int k = 1; k < 8; k++) mx = fmaxf(mx, x[k]);
            mx = wave_max64(mx);
            float s = 0.f;
            #pragma unroll
            for (int k = 0; k < 8; k++) s += expf(x[k] - mx);
            s = wave_sum64(s);
            float lse = mx + logf(s);
            if (lane == 0) lse_lds[q] = lse;
            float* wp = cost + q * QQ + lane * 3;
            wp[0] = -expf(g0 - lse);
            wp[1] = -expf(g1 - lse);
            wp[2] = -expf(g2 - lse);
            #pragma unroll
            for (int k = 0; k < 8; k++) x[k] = xn[k];
        }
    }
    __syncthreads();
    if (wv != 0) return;
    // single wave from here: in-wave LDS ordering via waitcnt, no barriers.

    // ---- solver state: 3 rows + 3 cols per lane ----
    float u0 = 0.f, u1 = 0.f, u2 = 0.f;   // row duals
    float v0 = 0.f, v1 = 0.f, v2 = 0.f;   // col duals
    int   xx0 = -1, xx1 = -1, xx2 = -1;   // col4row
    int   yy0 = -1, yy1 = -1, yy2 = -1;   // row4col

    const float* crow_base = cost + lane * 3;

    // ---- sequential JV shortest augmenting path (R2/R5 semantics) ----
    for (int cur = 0; cur < QQ; cur++) {
        float spc0 = NBIG, spc1 = NBIG, spc2 = NBIG;
        int   p0 = 0, p1 = 0, p2 = 0;
        unsigned kp0 = 0xFFFFFFFFu, kp1 = 0xFFFFFFFFu, kp2 = 0xFFFFFFFFu;
        int   sc0 = 0, sc1 = 0, sc2 = 0;
        unsigned long long SRm0 = 0, SRm1 = 0, SRm2 = 0;  // scanned-row masks (scalar)
        int   i = cur;
        float minVal = 0.f;
        int   sink, steps = 0;

        while (true) {
            {   // SR[i] (scalar)
                const int is = i >> 6, il = i & 63;
                if (is == 0)      SRm0 |= 1ull << il;
                else if (is == 1) SRm1 |= 1ull << il;
                else              SRm2 |= 1ull << il;
            }
            // one b96 read: lane's 3 cols of row i
            const float* cp = crow_base + i * QQ;
            const float cA = cp[0], cB = cp[1], cD = cp[2];
            // shadow work (independent of the LDS data):
            const float ui = GET_F3(u, i);
            const float fs = minVal - ui;
            const float sv0 = sc0 ? NBIG : fs - v0;
            const float sv1 = sc1 ? NBIG : fs - v1;
            const float sv2 = sc2 ? NBIG : fs - v2;

            // post-data: 1 add per slot, then key chain; spc/p updates parallel
            const float rA = cA + sv0;
            const float rB = cB + sv1;
            const float rD = cD + sv2;
            if (rA < spc0) { spc0 = rA; p0 = i; }
            if (rB < spc1) { spc1 = rB; p1 = i; }
            if (rD < spc2) { spc2 = rD; p2 = i; }
            const unsigned krA = (__float_as_uint(rA + 1.0f) & 0xFFFFFF00u) | (unsigned)lane;
            const unsigned krB = (__float_as_uint(rB + 1.0f) & 0xFFFFFF00u) | (unsigned)(lane + 64);
            const unsigned krD = (__float_as_uint(rD + 1.0f) & 0xFFFFFF00u) | (unsigned)(lane + 128);
            kp0 = umin_(kp0, krA);
            kp1 = umin_(kp1, krB);
            kp2 = umin_(kp2, krD);

            const unsigned pk = wave_min_pk(umin_(umin_(kp0, kp1), kp2));
            const int jstar = (int)(pk & 255u);
            const int os = jstar >> 6, ol = jstar & 63;

            // exact minVal from winner's spc; settle bookkeeping in shadow
            minVal = readlane_f(os == 0 ? spc0 : (os == 1 ? spc1 : spc2), ol);
            kp0 = (jstar == lane)       ? 0xFFFFFFFFu : kp0;
            kp1 = (jstar == lane + 64)  ? 0xFFFFFFFFu : kp1;
            kp2 = (jstar == lane + 128) ? 0xFFFFFFFFu : kp2;
            sc0 |= (jstar == lane);
            sc1 |= (jstar == lane + 64);
            sc2 |= (jstar == lane + 128);
            const int rj = readlane_i(os == 0 ? yy0 : (os == 1 ? yy1 : yy2), ol);
            steps++;
            if (rj < 0) { sink = jstar; break; }
            i = rj;
        }

        if (steps == 1) {
            // 1-step search: settled={sink} with spc[sink]==minVal exactly ->
            // v[sink] change is exactly 0; scanned rows = {cur}.
            u0 += (cur == lane) ? minVal : 0.f;
            u1 += (cur == lane + 64) ? minVal : 0.f;
            u2 += (cur == lane + 128) ? minVal : 0.f;
            SET_I3(yy, sink, cur);
            SET_I3(xx, cur, sink);
            continue;
        }

        // ---- dual updates ----
        u0 += (cur == lane) ? minVal : 0.f;
        u1 += (cur == lane + 64) ? minVal : 0.f;
        u2 += (cur == lane + 128) ? minVal : 0.f;
        spc_lds[lane] = spc0; spc_lds[lane + 64] = spc1; spc_lds[lane + 128] = spc2;
        const int f0 = (int)((SRm0 >> lane) & 1ull);
        const int f1 = (int)((SRm1 >> lane) & 1ull);
        const int f2 = (int)((SRm2 >> lane) & 1ull);
        if (f0 && lane != cur)         u0 += minVal - spc_lds[xx0];
        if (f1 && (lane + 64) != cur)  u1 += minVal - spc_lds[xx1];
        if (f2 && (lane + 128) != cur) u2 += minVal - spc_lds[xx2];
        if (sc0) v0 -= (minVal - spc0);
        if (sc1) v1 -= (minVal - spc1);
        if (sc2) v2 -= (minVal - spc2);

        // ---- augment along stored path ----
        int j = sink;
        while (true) {
            const int pj = GET_I3(p, j);
            SET_I3(yy, j, pj);
            const int nj = GET_I3(xx, pj);
            SET_I3(xx, pj, j);
            if (pj == cur) break;
            j = nj;
        }
    }

    // ---- CE partial: sum_r (lse[r] - pred[r][tgt[col4row[r]]]) ----
    float part = 0.f;
    {
        const int tc0 = tgt_lds[xx0], tc1 = tgt_lds[xx1], tc2 = tgt_lds[xx2];
        part += lse_lds[lane]       - predb[(size_t)lane * CC + tc0];
        part += lse_lds[lane + 64]  - predb[(size_t)(lane + 64) * CC + tc1];
        part += lse_lds[lane + 128] - predb[(size_t)(lane + 128) * CC + tc2];
    }
    part = wave_sum64(part);
    if (lane == 0) ws_part[b] = part;
}

__launch_bounds__(64)
__global__ void reduce_kernel(const float* __restrict__ ws_part,
                              float* __restrict__ out) {
    int lane = threadIdx.x;
    float s = ws_part[lane] + ws_part[lane + 64];
    s = wave_sum64(s);
    if (lane == 0) out[0] = s / (float)(BB * QQ);
}

extern "C" void kernel_launch(void* const* d_in, const int* in_sizes, int n_in,
                              void* d_out, int out_size, void* d_ws, size_t ws_size,
                              hipStream_t stream) {
    const float* pred = (const float*)d_in[0];
    const int* targets = (const int*)d_in[1];
    float* out = (float*)d_out;
    float* ws = (float*)d_ws;

    const int lds_bytes = (QQ * QQ + 3 * QQ) * (int)sizeof(float);  // 149760 B

    hipLaunchKernelGGL(hungarian_kernel, dim3(BB), dim3(256), lds_bytes, stream,
                       pred, targets, ws);
    hipLaunchKernelGGL(reduce_kernel, dim3(1), dim3(64), 0, stream, ws, out);
}